// Round 10
// baseline (176.432 us; speedup 1.0000x reference)
//
#include <hip/hip_runtime.h>

#define BATCH 16
#define NQ    16384      // N = 128*128
#define EPS_LN 1e-5f

typedef __attribute__((ext_vector_type(4))) short bf16x4;
typedef __attribute__((ext_vector_type(8))) short short8;
typedef __attribute__((ext_vector_type(4))) float f32x4;

#define MFMA16(a, b, c) __builtin_amdgcn_mfma_f32_16x16x32_bf16((a), (b), (c), 0, 0, 0)

__device__ __forceinline__ unsigned short f2bf(float f) {
    unsigned int u = __builtin_bit_cast(unsigned int, f);
    u += 0x7FFFu + ((u >> 16) & 1u);   // RNE
    return (unsigned short)(u >> 16);
}
// fast pack: round-half-up via +0x8000 then byte-perm (1 v_perm per 2 elements)
__device__ __forceinline__ unsigned int pk2r(float a, float b) {
    unsigned int ua = __builtin_bit_cast(unsigned int, a) + 0x8000u;
    unsigned int ub = __builtin_bit_cast(unsigned int, b) + 0x8000u;
    return __builtin_amdgcn_perm(ub, ua, 0x07060302u);  // low16=bf(a), high16=bf(b)
}
__device__ __forceinline__ bf16x4 pk4r(float a, float b, float c, float d) {
    unsigned long long v = (unsigned long long)pk2r(a, b) |
                           ((unsigned long long)pk2r(c, d) << 32);
    return __builtin_bit_cast(bf16x4, v);
}
__device__ __forceinline__ short8 cat8(bf16x4 lo, bf16x4 hi) {
    short8 r;
    r[0] = lo[0]; r[1] = lo[1]; r[2] = lo[2]; r[3] = lo[3];
    r[4] = hi[0]; r[5] = hi[1]; r[6] = hi[2]; r[7] = hi[3];
    return r;
}
// exp2 via __expf(x*ln2): folds to v_exp_f32 (numerics verified r8, absmax unchanged)
__device__ __forceinline__ float exp2fast(float x) {
    return __expf(x * 0.69314718055994530942f);
}
// k-order permutations (A/B k-slot consistency; round-3 analysis, verified)
__device__ __forceinline__ int perm64(int c) {
    int cc = c >> 4, q4c = (c >> 2) & 3, e = c & 3;
    return q4c * 16 + (cc >> 1) * 8 + (cc & 1) * 4 + e;
}
__device__ __forceinline__ int perm256(int n) {
    int tt = n >> 4, q4n = (n >> 2) & 3, e = n & 3;
    return q4n * 64 + (tt >> 1) * 8 + (tt & 1) * 4 + e;
}

// ---------------- prep: fragment-contiguous weight layouts ----------------
// (unchanged from round 6)
__global__ __launch_bounds__(256) void prep_kernel(
    const float* __restrict__ Wq, const float* __restrict__ Wo,
    const float* __restrict__ conv_w, const float* __restrict__ Wkv,
    unsigned short* __restrict__ Wq_p, unsigned short* __restrict__ Wo_p,
    unsigned short* __restrict__ Wc_f, unsigned short* __restrict__ Wkv_f)
{
    int idx = blockIdx.x * 256 + threadIdx.x;
    if (idx < 262144) {
        int e = idx & 7, lane = (idx >> 3) & 63, s = (idx >> 9) & 15;
        int r = (idx >> 13) & 7, nt = (idx >> 16) & 3;
        int k = r * 512 + s * 32 + (lane >> 4) * 8 + e;
        int cout = nt * 16 + (lane & 15);
        Wc_f[idx] = f2bf(conv_w[(size_t)k * 64 + cout]);
    } else if (idx < 278528) {
        int i = idx - 262144;
        int e = i & 7, lane = (i >> 3) & 63, s = (i >> 9) & 1, nt = i >> 10;
        int k = s * 32 + (lane >> 4) * 8 + e;
        int n = nt * 16 + (lane & 15);
        Wkv_f[i] = f2bf(Wkv[(size_t)k * 128 + n]);
    } else if (idx < 282624) {
        int i = idx - 278528;
        int c = i >> 6, d = i & 63;
        Wq_p[d * 64 + perm64(c)] = f2bf(Wq[c * 64 + d]);
    } else {
        int i = idx - 282624;
        int c = i >> 6, d = i & 63;
        Wo_p[d * 64 + perm64(c)] = f2bf(Wo[c * 64 + d]);
    }
}

// ---------------- kv_fused: conv8x8s8 + LN + KV projection, all MFMA ----------------
// (unchanged from round 6 — 16 waves, 2 stage->MFMA iterations)
__global__ __launch_bounds__(1024) void kv_fused(
    const float* __restrict__ inp,           // [B,16384,64]
    const unsigned short* __restrict__ Wc_f,
    const float* __restrict__ conv_b, const float* __restrict__ gamma,
    const float* __restrict__ beta,
    const unsigned short* __restrict__ Wkv_f, const float* __restrict__ bkv,
    unsigned short* __restrict__ Kf,   // [B,16384] fragment-contiguous
    unsigned short* __restrict__ Vf)   // [B,16384] fragment-contiguous
{
    __shared__ unsigned short Xa[2][4][16][520];  // [buf][rowgrp][patch][512+8] ~130 KiB
    __shared__ float Cb[4][16][68];               // partial conv sums per row-group
    __shared__ unsigned short yb[16][72];

    const int bp = blockIdx.x;
    const int b = bp >> 4, ph = bp & 15;
    const int t = threadIdx.x;
    const int w = t >> 6, lane = t & 63, l15 = lane & 15, q4 = lane >> 4;
    const int g  = w >> 2;        // row group 0..3 (rows g*2, g*2+1)
    const int ct = w & 3;         // cout tile

    const float* rowbase = inp + (size_t)bp * 8 * 8192;
    // staging: thread group sg (= t>>8 = g for this thread's wave) stages row sg*2+rr
    const int sg = t >> 8, st = t & 255;
    const float* rb2 = rowbase + (size_t)sg * 2 * 8192;

    float4 rg[8];
    #pragma unroll
    for (int i = 0; i < 8; ++i)
        rg[i] = *(const float4*)(rb2 + i * 1024 + st * 4);

    f32x4 acc0 = {0,0,0,0}, acc1 = {0,0,0,0};
    for (int rr = 0; rr < 2; ++rr) {
        __syncthreads();
        #pragma unroll
        for (int i = 0; i < 8; ++i) {
            const int e0 = i * 1024 + st * 4;
            unsigned int lo = pk2r(rg[i].x, rg[i].y);
            unsigned int hi = pk2r(rg[i].z, rg[i].w);
            *(uint2*)(&Xa[rr & 1][sg][e0 >> 9][e0 & 511]) = make_uint2(lo, hi);
        }
        if (rr < 1) {
            #pragma unroll
            for (int i = 0; i < 8; ++i)
                rg[i] = *(const float4*)(rb2 + 8192 + i * 1024 + st * 4);
        }
        __syncthreads();
        const int r = g * 2 + rr;
        const unsigned short* wrow = Wc_f + ((size_t)(ct * 8 + r) * 16) * 512 + lane * 8;
        #pragma unroll
        for (int s = 0; s < 16; ++s) {
            short8 af = *(const short8*)&Xa[rr & 1][g][l15][s * 32 + q4 * 8];
            short8 bf = *(const short8*)(wrow + s * 512);
            if (s & 1) acc1 = MFMA16(af, bf, acc1);
            else       acc0 = MFMA16(af, bf, acc0);
        }
    }
    f32x4 accT = acc0 + acc1;
    #pragma unroll
    for (int jj = 0; jj < 4; ++jj)
        Cb[g][q4 * 4 + jj][ct * 16 + l15] = accT[jj];
    __syncthreads();

    // LayerNorm: thread = (patch, grp), 4 channels each (first 4 waves)
    if (t < 256) {
        const int patch = t >> 4, gc = t & 15;
        float x[4], ssum = 0.f;
        #pragma unroll
        for (int cc = 0; cc < 4; ++cc) {
            const int c = gc + cc * 16;
            x[cc] = Cb[0][patch][c] + Cb[1][patch][c] + Cb[2][patch][c] + Cb[3][patch][c]
                  + conv_b[c];
            ssum += x[cc];
        }
        #pragma unroll
        for (int off = 8; off >= 1; off >>= 1) ssum += __shfl_xor(ssum, off, 16);
        const float mean = ssum * (1.f / 64.f);
        float v2 = 0.f;
        #pragma unroll
        for (int cc = 0; cc < 4; ++cc) { x[cc] -= mean; v2 += x[cc] * x[cc]; }
        #pragma unroll
        for (int off = 8; off >= 1; off >>= 1) v2 += __shfl_xor(v2, off, 16);
        const float rs = rsqrtf(v2 * (1.f / 64.f) + EPS_LN);
        #pragma unroll
        for (int cc = 0; cc < 4; ++cc) {
            const int c = gc + cc * 16;
            yb[patch][c] = f2bf(x[cc] * rs * gamma[c] + beta[c]);
        }
    }
    __syncthreads();

    // KV projection: M=16 patches, N=128, K=64 via MFMA; waves 0..7 -> n-tile w
    if (w < 8) {
        const int nt = w;
        f32x4 a2 = {0,0,0,0};
        #pragma unroll
        for (int s = 0; s < 2; ++s) {
            short8 af = *(const short8*)&yb[l15][s * 32 + q4 * 8];
            short8 bf = *(const short8*)(Wkv_f + ((nt * 2 + s) * 64 + lane) * 8);
            a2 = MFMA16(af, bf, a2);
        }
        const int n = nt * 16 + l15;
        const float bias = bkv[n];
        #pragma unroll
        for (int jj = 0; jj < 4; ++jj) {
            const int pg = ph * 16 + q4 * 4 + jj;   // patch index 0..255
            const float v = a2[jj] + bias;
            if (n < 64) {
                // K element (pg, n) -> fragment-contiguous slot
                const int p = perm64(n);            // q4p*16 + sp*8 + ep
                const int idx = (((pg >> 4) * 2 + ((p >> 3) & 1)) * 64 +
                                 (p >> 4) * 16 + (pg & 15)) * 8 + (p & 7);
                Kf[(size_t)b * 16384 + idx] = f2bf(v);
            } else {
                // V element (d = n-64, pg) -> fragment-contiguous slot
                const int d = n - 64;
                const int p = perm256(pg);          // q4p*64 + u*8 + ep
                const int idx = (((d >> 4) * 8 + ((p >> 3) & 7)) * 64 +
                                 (p >> 6) * 16 + (d & 15)) * 8 + (p & 7);
                Vf[(size_t)b * 16384 + idx] = f2bf(v);
            }
        }
    }
}

// ---------------- attention: fused S->exp->PV streaming loop (r6 shell) ----------------
// Round 10: shell reverted to r6 (512 thr, 8 waves, grid 1024, K+V in 64 KiB LDS —
// best measured at 43.1 µs; r9's 1024-thr block convoyed 16 waves and regressed).
// NEW: the S-phase and PV-phase are fused per K-fragment-group u: 8 S-MFMAs ->
// 16 exp+pack (transient) -> 8 PV-MFMAs into persistent aa/ab. The exp VALU of
// step u overlaps PV MFMAs of u and S-MFMAs of u+1 (independent chains), and
// pa/pk[8] (64 VGPRs) no longer live across a phase boundary. Occupancy is
// LDS-capped (2 blocks/CU) so VGPR can grow to 128 free of cost.
// NOTE: no min-waves occupancy hint (r1: it capped VGPR at 32 -> spills).
__global__ __launch_bounds__(512) void attn_mfma(
    const float* __restrict__ inp,
    const unsigned short* __restrict__ Wq_p,
    const float* __restrict__ bq,
    const unsigned short* __restrict__ Kf,   // [B,16384] fragment-contiguous
    const unsigned short* __restrict__ Vf,   // [B,16384] fragment-contiguous
    const unsigned short* __restrict__ Wo_p,
    const float* __restrict__ bo,
    float* __restrict__ out)
{
    __shared__ unsigned short Klds[16384];   // 32 KiB, linear fragment order
    __shared__ unsigned short Vlds[16384];   // 32 KiB, linear fragment order

    const int tid  = threadIdx.x;
    const int w    = tid >> 6;          // 0..7
    const int lane = tid & 63;
    const int l15  = lane & 15;
    const int q4   = lane >> 4;
    const int b    = blockIdx.x >> 6;   // 64 blocks per batch
    const int m0   = blockIdx.x * 256 + w * 32;   // group A: m0..+15, B: m0+16..+31

    // ---- stage K+V: linear memcpy, 4 x 16B per thread per buffer ----
    {
        const short8* Ks = (const short8*)(Kf + (size_t)b * 16384);
        const short8* Vs = (const short8*)(Vf + (size_t)b * 16384);
        short8* Kd = (short8*)Klds;
        short8* Vd = (short8*)Vlds;
        #pragma unroll
        for (int i = 0; i < 4; ++i) {
            Kd[tid + i * 512] = Ks[tid + i * 512];
            Vd[tid + i * 512] = Vs[tid + i * 512];
        }
    }

    const f32x4 zero = {0.f, 0.f, 0.f, 0.f};
    const float QSCALE = 0.125f * 1.44269504089f;   // 1/sqrt(64) * log2(e)

    // X load + Q projection for both query groups (overlaps staging)
    short8 qb[2][2];
    #pragma unroll
    for (int gq = 0; gq < 2; ++gq) {
        const float* xr = inp + (size_t)(m0 + gq * 16 + l15) * 64 + q4 * 4;
        short8 xb0, xb1;
        {
            float4 f0 = *(const float4*)(xr);
            float4 f1 = *(const float4*)(xr + 16);
            float4 f2 = *(const float4*)(xr + 32);
            float4 f3 = *(const float4*)(xr + 48);
            xb0 = cat8(pk4r(f0.x, f0.y, f0.z, f0.w), pk4r(f1.x, f1.y, f1.z, f1.w));
            xb1 = cat8(pk4r(f2.x, f2.y, f2.z, f2.w), pk4r(f3.x, f3.y, f3.z, f3.w));
        }
        bf16x4 q4s[4];
        #pragma unroll
        for (int t = 0; t < 4; ++t) {
            const unsigned short* wr = Wq_p + (t * 16 + l15) * 64 + q4 * 16;
            short8 w0 = *(const short8*)(wr);
            short8 w1 = *(const short8*)(wr + 8);
            f32x4 qa = MFMA16(w1, xb1, MFMA16(w0, xb0, zero));
            float4 bqv = *(const float4*)(bq + t * 16 + q4 * 4);
            q4s[t] = pk4r((qa[0] + bqv.x) * QSCALE, (qa[1] + bqv.y) * QSCALE,
                          (qa[2] + bqv.z) * QSCALE, (qa[3] + bqv.w) * QSCALE);
        }
        qb[gq][0] = cat8(q4s[0], q4s[1]);
        qb[gq][1] = cat8(q4s[2], q4s[3]);
    }

    __syncthreads();   // K/V staged

    // Fused S -> exp2 -> PV streaming loop.
    // Scores bounded (LayerNorm'd K, glorot q): fixed-max exp2 is overflow-safe.
    const unsigned short* Kg = Klds + lane * 8;
    const unsigned short* Vg = Vlds + lane * 8;
    float sma = 0.f, smb = 0.f;
    f32x4 aa[4] = {zero, zero, zero, zero};
    f32x4 ab[4] = {zero, zero, zero, zero};
    #pragma unroll
    for (int u = 0; u < 8; ++u) {
        short8 k0 = *(const short8*)(Kg + (4 * u    ) * 512);
        short8 k1 = *(const short8*)(Kg + (4 * u + 1) * 512);
        short8 k2 = *(const short8*)(Kg + (4 * u + 2) * 512);
        short8 k3 = *(const short8*)(Kg + (4 * u + 3) * 512);
        f32x4 a0 = MFMA16(k1, qb[0][1], MFMA16(k0, qb[0][0], zero));
        f32x4 a1 = MFMA16(k3, qb[0][1], MFMA16(k2, qb[0][0], zero));
        f32x4 b0 = MFMA16(k1, qb[1][1], MFMA16(k0, qb[1][0], zero));
        f32x4 b1 = MFMA16(k3, qb[1][1], MFMA16(k2, qb[1][0], zero));
        float ea0 = exp2fast(a0[0]), ea1 = exp2fast(a0[1]);
        float ea2 = exp2fast(a0[2]), ea3 = exp2fast(a0[3]);
        float ea4 = exp2fast(a1[0]), ea5 = exp2fast(a1[1]);
        float ea6 = exp2fast(a1[2]), ea7 = exp2fast(a1[3]);
        sma += ((ea0 + ea1) + (ea2 + ea3)) + ((ea4 + ea5) + (ea6 + ea7));
        short8 pua = cat8(pk4r(ea0, ea1, ea2, ea3), pk4r(ea4, ea5, ea6, ea7));
        float eb0 = exp2fast(b0[0]), eb1 = exp2fast(b0[1]);
        float eb2 = exp2fast(b0[2]), eb3 = exp2fast(b0[3]);
        float eb4 = exp2fast(b1[0]), eb5 = exp2fast(b1[1]);
        float eb6 = exp2fast(b1[2]), eb7 = exp2fast(b1[3]);
        smb += ((eb0 + eb1) + (eb2 + eb3)) + ((eb4 + eb5) + (eb6 + eb7));
        short8 pub = cat8(pk4r(eb0, eb1, eb2, eb3), pk4r(eb4, eb5, eb6, eb7));
        // PV for this u: V fragment loaded once, consumed by both query groups
        #pragma unroll
        for (int dt = 0; dt < 4; ++dt) {
            short8 vf = *(const short8*)(Vg + (dt * 8 + u) * 512);
            aa[dt] = MFMA16(vf, pua, aa[dt]);
            ab[dt] = MFMA16(vf, pub, ab[dt]);
        }
    }
    sma += __shfl_xor(sma, 16);
    sma += __shfl_xor(sma, 32);
    smb += __shfl_xor(smb, 16);
    smb += __shfl_xor(smb, 32);
    const float inva = 1.f / sma;
    const float invb = 1.f / smb;

    // normalize + pack O
    short8 oa[2], ob[2];
    {
        bf16x4 o4a[4], o4b[4];
        #pragma unroll
        for (int dt = 0; dt < 4; ++dt) {
            o4a[dt] = pk4r(aa[dt][0] * inva, aa[dt][1] * inva,
                           aa[dt][2] * inva, aa[dt][3] * inva);
            o4b[dt] = pk4r(ab[dt][0] * invb, ab[dt][1] * invb,
                           ab[dt][2] * invb, ab[dt][3] * invb);
        }
        oa[0] = cat8(o4a[0], o4a[1]);
        oa[1] = cat8(o4a[2], o4a[3]);
        ob[0] = cat8(o4b[0], o4b[1]);
        ob[1] = cat8(o4b[2], o4b[3]);
    }
    // out^T = Wo . O^T — Wo fragments shared between groups
    float* orowa = out + (size_t)(m0 + l15) * 64 + q4 * 4;
    float* orowb = out + (size_t)(m0 + 16 + l15) * 64 + q4 * 4;
    #pragma unroll
    for (int et = 0; et < 4; ++et) {
        const unsigned short* wr = Wo_p + (et * 16 + l15) * 64 + q4 * 16;
        short8 w0 = *(const short8*)(wr);
        short8 w1 = *(const short8*)(wr + 8);
        float4 bov = *(const float4*)(bo + et * 16 + q4 * 4);
        f32x4 acca = MFMA16(w1, oa[1], MFMA16(w0, oa[0], zero));
        f32x4 accb = MFMA16(w1, ob[1], MFMA16(w0, ob[0], zero));
        float4 ra = { acca[0] + bov.x, acca[1] + bov.y, acca[2] + bov.z, acca[3] + bov.w };
        float4 rb = { accb[0] + bov.x, accb[1] + bov.y, accb[2] + bov.z, accb[3] + bov.w };
        *(float4*)(orowa + et * 16) = ra;
        *(float4*)(orowb + et * 16) = rb;
    }
}

extern "C" void kernel_launch(void* const* d_in, const int* in_sizes, int n_in,
                              void* d_out, int out_size, void* d_ws, size_t ws_size,
                              hipStream_t stream) {
    const float* inp     = (const float*)d_in[0];
    const float* Wq      = (const float*)d_in[1];
    const float* bq      = (const float*)d_in[2];
    const float* Wkv     = (const float*)d_in[3];
    const float* bkv     = (const float*)d_in[4];
    const float* Wo      = (const float*)d_in[5];
    const float* bo      = (const float*)d_in[6];
    const float* conv_w  = (const float*)d_in[7];
    const float* conv_b  = (const float*)d_in[8];
    const float* gamma   = (const float*)d_in[9];
    const float* beta    = (const float*)d_in[10];

    char* ws = (char*)d_ws;
    unsigned short* Kf    = (unsigned short*)(ws);                 // 512 KiB slot (32 KiB/batch used)
    unsigned short* Vf    = (unsigned short*)(ws + 524288);        // 512 KiB slot
    unsigned short* Wq_p  = (unsigned short*)(ws + 1048576);       // 8 KiB
    unsigned short* Wo_p  = (unsigned short*)(ws + 1056768);       // 8 KiB
    unsigned short* Wc_f  = (unsigned short*)(ws + 1064960);       // 512 KiB
    unsigned short* Wkv_f = (unsigned short*)(ws + 1589248);       // 32 KiB

    prep_kernel<<<1120, 256, 0, stream>>>(Wq, Wo, conv_w, Wkv, Wq_p, Wo_p, Wc_f, Wkv_f);
    kv_fused<<<256, 1024, 0, stream>>>(inp, Wc_f, conv_b, gamma, beta, Wkv_f, bkv, Kf, Vf);
    attn_mfma<<<1024, 512, 0, stream>>>(inp, Wq_p, bq, Kf, Vf, Wo_p, bo, (float*)d_out);
}

// Round 11
// 170.965 us; speedup vs baseline: 1.0320x; 1.0320x over previous
//
#include <hip/hip_runtime.h>

#define BATCH 16
#define NQ    16384      // N = 128*128
#define EPS_LN 1e-5f

typedef __attribute__((ext_vector_type(4))) short bf16x4;
typedef __attribute__((ext_vector_type(8))) short short8;
typedef __attribute__((ext_vector_type(4))) float f32x4;

#define MFMA16(a, b, c) __builtin_amdgcn_mfma_f32_16x16x32_bf16((a), (b), (c), 0, 0, 0)

__device__ __forceinline__ unsigned short f2bf(float f) {
    unsigned int u = __builtin_bit_cast(unsigned int, f);
    u += 0x7FFFu + ((u >> 16) & 1u);   // RNE
    return (unsigned short)(u >> 16);
}
// fast pack: round-half-up via +0x8000 then byte-perm (1 v_perm per 2 elements)
__device__ __forceinline__ unsigned int pk2r(float a, float b) {
    unsigned int ua = __builtin_bit_cast(unsigned int, a) + 0x8000u;
    unsigned int ub = __builtin_bit_cast(unsigned int, b) + 0x8000u;
    return __builtin_amdgcn_perm(ub, ua, 0x07060302u);  // low16=bf(a), high16=bf(b)
}
__device__ __forceinline__ bf16x4 pk4r(float a, float b, float c, float d) {
    unsigned long long v = (unsigned long long)pk2r(a, b) |
                           ((unsigned long long)pk2r(c, d) << 32);
    return __builtin_bit_cast(bf16x4, v);
}
__device__ __forceinline__ short8 cat8(bf16x4 lo, bf16x4 hi) {
    short8 r;
    r[0] = lo[0]; r[1] = lo[1]; r[2] = lo[2]; r[3] = lo[3];
    r[4] = hi[0]; r[5] = hi[1]; r[6] = hi[2]; r[7] = hi[3];
    return r;
}
// exp2 via __expf(x*ln2): folds to v_exp_f32 (numerics verified r8-r10, absmax unchanged)
__device__ __forceinline__ float exp2fast(float x) {
    return __expf(x * 0.69314718055994530942f);
}
// k-order permutations (A/B k-slot consistency; round-3 analysis, verified)
__device__ __forceinline__ int perm64(int c) {
    int cc = c >> 4, q4c = (c >> 2) & 3, e = c & 3;
    return q4c * 16 + (cc >> 1) * 8 + (cc & 1) * 4 + e;
}
__device__ __forceinline__ int perm256(int n) {
    int tt = n >> 4, q4n = (n >> 2) & 3, e = n & 3;
    return q4n * 64 + (tt >> 1) * 8 + (tt & 1) * 4 + e;
}

// ---------------- prep: fragment-contiguous weight layouts ----------------
// (unchanged)
__global__ __launch_bounds__(256) void prep_kernel(
    const float* __restrict__ Wq, const float* __restrict__ Wo,
    const float* __restrict__ conv_w, const float* __restrict__ Wkv,
    unsigned short* __restrict__ Wq_p, unsigned short* __restrict__ Wo_p,
    unsigned short* __restrict__ Wc_f, unsigned short* __restrict__ Wkv_f)
{
    int idx = blockIdx.x * 256 + threadIdx.x;
    if (idx < 262144) {
        int e = idx & 7, lane = (idx >> 3) & 63, s = (idx >> 9) & 15;
        int r = (idx >> 13) & 7, nt = (idx >> 16) & 3;
        int k = r * 512 + s * 32 + (lane >> 4) * 8 + e;
        int cout = nt * 16 + (lane & 15);
        Wc_f[idx] = f2bf(conv_w[(size_t)k * 64 + cout]);
    } else if (idx < 278528) {
        int i = idx - 262144;
        int e = i & 7, lane = (i >> 3) & 63, s = (i >> 9) & 1, nt = i >> 10;
        int k = s * 32 + (lane >> 4) * 8 + e;
        int n = nt * 16 + (lane & 15);
        Wkv_f[i] = f2bf(Wkv[(size_t)k * 128 + n]);
    } else if (idx < 282624) {
        int i = idx - 278528;
        int c = i >> 6, d = i & 63;
        Wq_p[d * 64 + perm64(c)] = f2bf(Wq[c * 64 + d]);
    } else {
        int i = idx - 282624;
        int c = i >> 6, d = i & 63;
        Wo_p[d * 64 + perm64(c)] = f2bf(Wo[c * 64 + d]);
    }
}

// ---------------- kv_fused: conv8x8s8 + LN + KV projection, half-width blocks ----------------
// Round 11: grid 512 = (b, ph, half). Each block handles 8 patches (one half of a
// patch-row): stages 8 half-rows of 16 KB (was 8 x 32 KB), LN is per-patch so no
// cross-block reduction. 2 blocks/CU (LDS ~76 KB): one block's MFMA overlaps the
// other's staging. M=16 MFMA tiles are half-filled (A rows 8-15 alias 0-7 via
// l15&7; writes guarded q4<2) — conv MFMA count doubles but staging dominates.
__global__ __launch_bounds__(1024) void kv_fused(
    const float* __restrict__ inp,           // [B,16384,64]
    const unsigned short* __restrict__ Wc_f,
    const float* __restrict__ conv_b, const float* __restrict__ gamma,
    const float* __restrict__ beta,
    const unsigned short* __restrict__ Wkv_f, const float* __restrict__ bkv,
    unsigned short* __restrict__ Kf,   // [B,16384] fragment-contiguous
    unsigned short* __restrict__ Vf)   // [B,16384] fragment-contiguous
{
    __shared__ unsigned short Xa[2][4][8][520];  // [buf][rowgrp][patch][512+8] ~65 KiB
    __shared__ float Cb[4][8][68];               // partial conv sums per row-group
    __shared__ unsigned short yb[8][72];

    const int bph = blockIdx.x;
    const int bp = bph >> 1, half = bph & 1;
    const int b = bp >> 4, ph = bp & 15;
    const int t = threadIdx.x;
    const int w = t >> 6, lane = t & 63, l15 = lane & 15, q4 = lane >> 4;
    const int g  = w >> 2;        // row group 0..3 (rows g*2, g*2+1)
    const int ct = w & 3;         // cout tile

    // half-row base: patch-row bp, columns half*64..half*64+63
    const float* rb2 = inp + (size_t)bp * 65536 + (size_t)half * 4096;
    // staging: thread group sg (= g for this thread's wave) stages row sg*2+rr
    const int sg = t >> 8, st = t & 255;

    float4 rg[4];
    #pragma unroll
    for (int i = 0; i < 4; ++i)
        rg[i] = *(const float4*)(rb2 + (size_t)(sg * 2) * 8192 + i * 1024 + st * 4);

    f32x4 acc0 = {0,0,0,0}, acc1 = {0,0,0,0};
    for (int rr = 0; rr < 2; ++rr) {
        __syncthreads();
        #pragma unroll
        for (int i = 0; i < 4; ++i) {
            const int e0 = i * 1024 + st * 4;
            unsigned int lo = pk2r(rg[i].x, rg[i].y);
            unsigned int hi = pk2r(rg[i].z, rg[i].w);
            *(uint2*)(&Xa[rr & 1][sg][e0 >> 9][e0 & 511]) = make_uint2(lo, hi);
        }
        if (rr < 1) {
            #pragma unroll
            for (int i = 0; i < 4; ++i)
                rg[i] = *(const float4*)(rb2 + (size_t)(sg * 2 + 1) * 8192 + i * 1024 + st * 4);
        }
        __syncthreads();
        const int r = g * 2 + rr;
        const unsigned short* wrow = Wc_f + ((size_t)(ct * 8 + r) * 16) * 512 + lane * 8;
        #pragma unroll
        for (int s = 0; s < 16; ++s) {
            short8 af = *(const short8*)&Xa[rr & 1][g][l15 & 7][s * 32 + q4 * 8];
            short8 bf = *(const short8*)(wrow + s * 512);
            if (s & 1) acc1 = MFMA16(af, bf, acc1);
            else       acc0 = MFMA16(af, bf, acc0);
        }
    }
    f32x4 accT = acc0 + acc1;
    if (q4 < 2) {    // valid patches 0..7 only (D rows 8-15 are duplicates)
        #pragma unroll
        for (int jj = 0; jj < 4; ++jj)
            Cb[g][q4 * 4 + jj][ct * 16 + l15] = accT[jj];
    }
    __syncthreads();

    // LayerNorm: thread = (patch 0..7, grp), 4 channels each (first 2 waves)
    if (t < 128) {
        const int patch = t >> 4, gc = t & 15;
        float x[4], ssum = 0.f;
        #pragma unroll
        for (int cc = 0; cc < 4; ++cc) {
            const int c = gc + cc * 16;
            x[cc] = Cb[0][patch][c] + Cb[1][patch][c] + Cb[2][patch][c] + Cb[3][patch][c]
                  + conv_b[c];
            ssum += x[cc];
        }
        #pragma unroll
        for (int off = 8; off >= 1; off >>= 1) ssum += __shfl_xor(ssum, off, 16);
        const float mean = ssum * (1.f / 64.f);
        float v2 = 0.f;
        #pragma unroll
        for (int cc = 0; cc < 4; ++cc) { x[cc] -= mean; v2 += x[cc] * x[cc]; }
        #pragma unroll
        for (int off = 8; off >= 1; off >>= 1) v2 += __shfl_xor(v2, off, 16);
        const float rs = rsqrtf(v2 * (1.f / 64.f) + EPS_LN);
        #pragma unroll
        for (int cc = 0; cc < 4; ++cc) {
            const int c = gc + cc * 16;
            yb[patch][c] = f2bf(x[cc] * rs * gamma[c] + beta[c]);
        }
    }
    __syncthreads();

    // KV projection: M=16 (8 valid patches), N=128, K=64; waves 0..7 -> n-tile w
    if (w < 8) {
        const int nt = w;
        f32x4 a2 = {0,0,0,0};
        #pragma unroll
        for (int s = 0; s < 2; ++s) {
            short8 af = *(const short8*)&yb[l15 & 7][s * 32 + q4 * 8];
            short8 bf = *(const short8*)(Wkv_f + ((nt * 2 + s) * 64 + lane) * 8);
            a2 = MFMA16(af, bf, a2);
        }
        const int n = nt * 16 + l15;
        const float bias = bkv[n];
        if (q4 < 2) {    // valid patches only
            #pragma unroll
            for (int jj = 0; jj < 4; ++jj) {
                const int pg = ph * 16 + half * 8 + q4 * 4 + jj;   // global patch 0..255
                const float v = a2[jj] + bias;
                if (n < 64) {
                    const int p = perm64(n);
                    const int idx = (((pg >> 4) * 2 + ((p >> 3) & 1)) * 64 +
                                     (p >> 4) * 16 + (pg & 15)) * 8 + (p & 7);
                    Kf[(size_t)b * 16384 + idx] = f2bf(v);
                } else {
                    const int d = n - 64;
                    const int p = perm256(pg);
                    const int idx = (((d >> 4) * 8 + ((p >> 3) & 7)) * 64 +
                                     (p >> 6) * 16 + (d & 15)) * 8 + (p & 7);
                    Vf[(size_t)b * 16384 + idx] = f2bf(v);
                }
            }
        }
    }
}

// ---------------- attention: r6 structure (measured best: 43.1 us) ----------------
// K+V staged in 64 KiB LDS (linear fragment order, conflict-free), 512 thr = 8
// waves, ILP-2 (32 queries/wave), streaming fixed-max softmax as a SEPARATE
// S-phase (r10's fused S->PV serialized in regalloc and regressed; phase-split
// gives the scheduler 64 independent MFMAs per phase). exp2 QSCALE fold kept.
// NOTE: no min-waves occupancy hint (r1: it capped VGPR at 32 -> spills).
__global__ __launch_bounds__(512) void attn_mfma(
    const float* __restrict__ inp,
    const unsigned short* __restrict__ Wq_p,
    const float* __restrict__ bq,
    const unsigned short* __restrict__ Kf,   // [B,16384] fragment-contiguous
    const unsigned short* __restrict__ Vf,   // [B,16384] fragment-contiguous
    const unsigned short* __restrict__ Wo_p,
    const float* __restrict__ bo,
    float* __restrict__ out)
{
    __shared__ unsigned short Klds[16384];   // 32 KiB, linear fragment order
    __shared__ unsigned short Vlds[16384];   // 32 KiB, linear fragment order

    const int tid  = threadIdx.x;
    const int w    = tid >> 6;          // 0..7
    const int lane = tid & 63;
    const int l15  = lane & 15;
    const int q4   = lane >> 4;
    const int b    = blockIdx.x >> 6;   // 64 blocks per batch
    const int m0   = blockIdx.x * 256 + w * 32;   // group A: m0..+15, B: m0+16..+31

    // ---- stage K+V: linear memcpy, 4 x 16B per thread per buffer ----
    {
        const short8* Ks = (const short8*)(Kf + (size_t)b * 16384);
        const short8* Vs = (const short8*)(Vf + (size_t)b * 16384);
        short8* Kd = (short8*)Klds;
        short8* Vd = (short8*)Vlds;
        #pragma unroll
        for (int i = 0; i < 4; ++i) {
            Kd[tid + i * 512] = Ks[tid + i * 512];
            Vd[tid + i * 512] = Vs[tid + i * 512];
        }
    }

    const f32x4 zero = {0.f, 0.f, 0.f, 0.f};
    const float QSCALE = 0.125f * 1.44269504089f;   // 1/sqrt(64) * log2(e)

    // X load + Q projection for both query groups (overlaps staging)
    short8 qb[2][2];
    #pragma unroll
    for (int gq = 0; gq < 2; ++gq) {
        const float* xr = inp + (size_t)(m0 + gq * 16 + l15) * 64 + q4 * 4;
        short8 xb0, xb1;
        {
            float4 f0 = *(const float4*)(xr);
            float4 f1 = *(const float4*)(xr + 16);
            float4 f2 = *(const float4*)(xr + 32);
            float4 f3 = *(const float4*)(xr + 48);
            xb0 = cat8(pk4r(f0.x, f0.y, f0.z, f0.w), pk4r(f1.x, f1.y, f1.z, f1.w));
            xb1 = cat8(pk4r(f2.x, f2.y, f2.z, f2.w), pk4r(f3.x, f3.y, f3.z, f3.w));
        }
        bf16x4 q4s[4];
        #pragma unroll
        for (int t = 0; t < 4; ++t) {
            const unsigned short* wr = Wq_p + (t * 16 + l15) * 64 + q4 * 16;
            short8 w0 = *(const short8*)(wr);
            short8 w1 = *(const short8*)(wr + 8);
            f32x4 qa = MFMA16(w1, xb1, MFMA16(w0, xb0, zero));
            float4 bqv = *(const float4*)(bq + t * 16 + q4 * 4);
            q4s[t] = pk4r((qa[0] + bqv.x) * QSCALE, (qa[1] + bqv.y) * QSCALE,
                          (qa[2] + bqv.z) * QSCALE, (qa[3] + bqv.w) * QSCALE);
        }
        qb[gq][0] = cat8(q4s[0], q4s[1]);
        qb[gq][1] = cat8(q4s[2], q4s[3]);
    }

    __syncthreads();   // K/V staged

    // S^T = K . Q^T, fused with streaming exp2+sum+pack (scores consumed immediately)
    // Scores bounded (LayerNorm'd K, glorot q): fixed-max exp2 is overflow-safe.
    const unsigned short* Kg = Klds + lane * 8;
    float sma = 0.f, smb = 0.f;
    short8 pa[8], pk[8];
    #pragma unroll
    for (int u = 0; u < 8; ++u) {
        short8 k0 = *(const short8*)(Kg + (4 * u    ) * 512);
        short8 k1 = *(const short8*)(Kg + (4 * u + 1) * 512);
        short8 k2 = *(const short8*)(Kg + (4 * u + 2) * 512);
        short8 k3 = *(const short8*)(Kg + (4 * u + 3) * 512);
        f32x4 a0 = MFMA16(k1, qb[0][1], MFMA16(k0, qb[0][0], zero));
        f32x4 a1 = MFMA16(k3, qb[0][1], MFMA16(k2, qb[0][0], zero));
        f32x4 b0 = MFMA16(k1, qb[1][1], MFMA16(k0, qb[1][0], zero));
        f32x4 b1 = MFMA16(k3, qb[1][1], MFMA16(k2, qb[1][0], zero));
        float ea0 = exp2fast(a0[0]), ea1 = exp2fast(a0[1]);
        float ea2 = exp2fast(a0[2]), ea3 = exp2fast(a0[3]);
        float ea4 = exp2fast(a1[0]), ea5 = exp2fast(a1[1]);
        float ea6 = exp2fast(a1[2]), ea7 = exp2fast(a1[3]);
        sma += ((ea0 + ea1) + (ea2 + ea3)) + ((ea4 + ea5) + (ea6 + ea7));
        pa[u] = cat8(pk4r(ea0, ea1, ea2, ea3), pk4r(ea4, ea5, ea6, ea7));
        float eb0 = exp2fast(b0[0]), eb1 = exp2fast(b0[1]);
        float eb2 = exp2fast(b0[2]), eb3 = exp2fast(b0[3]);
        float eb4 = exp2fast(b1[0]), eb5 = exp2fast(b1[1]);
        float eb6 = exp2fast(b1[2]), eb7 = exp2fast(b1[3]);
        smb += ((eb0 + eb1) + (eb2 + eb3)) + ((eb4 + eb5) + (eb6 + eb7));
        pk[u] = cat8(pk4r(eb0, eb1, eb2, eb3), pk4r(eb4, eb5, eb6, eb7));
    }
    sma += __shfl_xor(sma, 16);
    sma += __shfl_xor(sma, 32);
    smb += __shfl_xor(smb, 16);
    smb += __shfl_xor(smb, 32);
    const float inva = 1.f / sma;
    const float invb = 1.f / smb;

    // O^T = V^T . P^T — each V fragment loaded from LDS once, used by both groups
    const unsigned short* Vg = Vlds + lane * 8;
    short8 oa[2], ob[2];
    {
        bf16x4 o4a[4], o4b[4];
        #pragma unroll
        for (int dt = 0; dt < 4; ++dt) {
            f32x4 aa = zero, ab = zero;
            #pragma unroll
            for (int u = 0; u < 8; ++u) {
                short8 vf = *(const short8*)(Vg + (dt * 8 + u) * 512);
                aa = MFMA16(vf, pa[u], aa);
                ab = MFMA16(vf, pk[u], ab);
            }
            o4a[dt] = pk4r(aa[0] * inva, aa[1] * inva, aa[2] * inva, aa[3] * inva);
            o4b[dt] = pk4r(ab[0] * invb, ab[1] * invb, ab[2] * invb, ab[3] * invb);
        }
        oa[0] = cat8(o4a[0], o4a[1]);
        oa[1] = cat8(o4a[2], o4a[3]);
        ob[0] = cat8(o4b[0], o4b[1]);
        ob[1] = cat8(o4b[2], o4b[3]);
    }
    // out^T = Wo . O^T — Wo fragments shared between groups
    float* orowa = out + (size_t)(m0 + l15) * 64 + q4 * 4;
    float* orowb = out + (size_t)(m0 + 16 + l15) * 64 + q4 * 4;
    #pragma unroll
    for (int et = 0; et < 4; ++et) {
        const unsigned short* wr = Wo_p + (et * 16 + l15) * 64 + q4 * 16;
        short8 w0 = *(const short8*)(wr);
        short8 w1 = *(const short8*)(wr + 8);
        float4 bov = *(const float4*)(bo + et * 16 + q4 * 4);
        f32x4 acca = MFMA16(w1, oa[1], MFMA16(w0, oa[0], zero));
        f32x4 accb = MFMA16(w1, ob[1], MFMA16(w0, ob[0], zero));
        float4 ra = { acca[0] + bov.x, acca[1] + bov.y, acca[2] + bov.z, acca[3] + bov.w };
        float4 rb = { accb[0] + bov.x, accb[1] + bov.y, accb[2] + bov.z, accb[3] + bov.w };
        *(float4*)(orowa + et * 16) = ra;
        *(float4*)(orowb + et * 16) = rb;
    }
}

extern "C" void kernel_launch(void* const* d_in, const int* in_sizes, int n_in,
                              void* d_out, int out_size, void* d_ws, size_t ws_size,
                              hipStream_t stream) {
    const float* inp     = (const float*)d_in[0];
    const float* Wq      = (const float*)d_in[1];
    const float* bq      = (const float*)d_in[2];
    const float* Wkv     = (const float*)d_in[3];
    const float* bkv     = (const float*)d_in[4];
    const float* Wo      = (const float*)d_in[5];
    const float* bo      = (const float*)d_in[6];
    const float* conv_w  = (const float*)d_in[7];
    const float* conv_b  = (const float*)d_in[8];
    const float* gamma   = (const float*)d_in[9];
    const float* beta    = (const float*)d_in[10];

    char* ws = (char*)d_ws;
    unsigned short* Kf    = (unsigned short*)(ws);                 // 512 KiB slot (32 KiB/batch used)
    unsigned short* Vf    = (unsigned short*)(ws + 524288);        // 512 KiB slot
    unsigned short* Wq_p  = (unsigned short*)(ws + 1048576);       // 8 KiB
    unsigned short* Wo_p  = (unsigned short*)(ws + 1056768);       // 8 KiB
    unsigned short* Wc_f  = (unsigned short*)(ws + 1064960);       // 512 KiB
    unsigned short* Wkv_f = (unsigned short*)(ws + 1589248);       // 32 KiB

    prep_kernel<<<1120, 256, 0, stream>>>(Wq, Wo, conv_w, Wkv, Wq_p, Wo_p, Wc_f, Wkv_f);
    kv_fused<<<512, 1024, 0, stream>>>(inp, Wc_f, conv_b, gamma, beta, Wkv_f, bkv, Kf, Vf);
    attn_mfma<<<1024, 512, 0, stream>>>(inp, Wq_p, bq, Kf, Vf, Wo_p, bo, (float*)d_out);
}